// Round 13
// baseline (753.156 us; speedup 1.0000x reference)
//
#include <hip/hip_runtime.h>
#include <hip/hip_bf16.h>
#include <math.h>

constexpr int BATCH = 256;
constexpr int SEQ   = 128;
constexpr int FEAT  = 512;
constexpr int HID   = 512;
constexpr int G3    = 1536;

typedef __bf16 bf16x8 __attribute__((ext_vector_type(8)));
typedef float  f32x4  __attribute__((ext_vector_type(4)));
typedef int    i32x4v __attribute__((ext_vector_type(4)));

// ---------------------------------------------------------------------------
// fp32 -> bf16 convert (vectorized, 8/thread)
// ---------------------------------------------------------------------------
__global__ __launch_bounds__(256) void convert_bf16(
    const float* __restrict__ in, __hip_bfloat16* __restrict__ out, int n)
{
  int i = (blockIdx.x * 256 + threadIdx.x) * 8;
  if (i >= n) return;
  float4 v0 = *(const float4*)&in[i];
  float4 v1 = *(const float4*)&in[i + 4];
  __hip_bfloat16 o[8];
  o[0] = (__hip_bfloat16)v0.x; o[1] = (__hip_bfloat16)v0.y;
  o[2] = (__hip_bfloat16)v0.z; o[3] = (__hip_bfloat16)v0.w;
  o[4] = (__hip_bfloat16)v1.x; o[5] = (__hip_bfloat16)v1.y;
  o[6] = (__hip_bfloat16)v1.z; o[7] = (__hip_bfloat16)v1.w;
  *(int4*)&out[i] = *(int4*)o;
}

// ---------------------------------------------------------------------------
// transpose + convert: in[512][1536] f32 -> outT[1536][512] bf16
// ---------------------------------------------------------------------------
__global__ __launch_bounds__(256) void transpose_convert(
    const float* __restrict__ in, __hip_bfloat16* __restrict__ outT)
{
  __shared__ float tile[32][33];
  const int c0 = blockIdx.x * 32;
  const int r0 = blockIdx.y * 32;
  const int tid = threadIdx.x;
  {
    int row = tid >> 3, c4 = tid & 7;
    float4 v = *(const float4*)&in[(size_t)(r0 + row) * G3 + c0 + c4 * 4];
    tile[row][c4 * 4 + 0] = v.x;
    tile[row][c4 * 4 + 1] = v.y;
    tile[row][c4 * 4 + 2] = v.z;
    tile[row][c4 * 4 + 3] = v.w;
  }
  __syncthreads();
  {
    int rowT = tid >> 3, c4 = tid & 7;
    __hip_bfloat16 o[4];
#pragma unroll
    for (int e = 0; e < 4; ++e)
      o[e] = (__hip_bfloat16)tile[c4 * 4 + e][rowT];
    *(int2*)&outT[(size_t)(c0 + rowT) * FEAT + r0 + c4 * 4] = *(int2*)o;
  }
}

// ---------------------------------------------------------------------------
// proj: 128x128 tile, BK=64, single-buffered global_load_lds staging with
// XOR source/read swizzle; __launch_bounds__(256,3) (R12: 92->77 us).
// ---------------------------------------------------------------------------
__global__ __launch_bounds__(256, 3) void proj_mfma(
    const __hip_bfloat16* __restrict__ xb, const __hip_bfloat16* __restrict__ WkT,
    const float* __restrict__ bias, __hip_bfloat16* __restrict__ xp)
{
  __shared__ __align__(16) __hip_bfloat16 As[128 * 64];
  __shared__ __align__(16) __hip_bfloat16 Bs[128 * 64];

  const int tid = threadIdx.x;
  const int wave = tid >> 6, l = tid & 63;
  const int wm = wave >> 1, wn = wave & 1;
  const int m0 = blockIdx.y * 128;
  const int n0 = blockIdx.x * 128;
  const int lr = l & 15, lh = l >> 4;
  const int swz = lr & 7;

  const int srow = l >> 3;
  const int schk = l & 7;
  const int wrow = wave * 32;

  f32x4 acc[4][4] = {};

  for (int k0 = 0; k0 < FEAT; k0 += 64) {
    __syncthreads();
#pragma unroll
    for (int i = 0; i < 4; ++i) {
      int r = wrow + i * 8 + srow;
      const __hip_bfloat16* srcA = &xb[(size_t)(m0 + r) * FEAT + k0 + ((schk ^ srow) * 8)];
      __builtin_amdgcn_global_load_lds(
          (const __attribute__((address_space(1))) void*)srcA,
          (__attribute__((address_space(3))) void*)&As[(wrow + i * 8) * 64], 16, 0, 0);
    }
#pragma unroll
    for (int i = 0; i < 4; ++i) {
      int r = wrow + i * 8 + srow;
      const __hip_bfloat16* srcB = &WkT[(size_t)(n0 + r) * FEAT + k0 + ((schk ^ srow) * 8)];
      __builtin_amdgcn_global_load_lds(
          (const __attribute__((address_space(1))) void*)srcB,
          (__attribute__((address_space(3))) void*)&Bs[(wrow + i * 8) * 64], 16, 0, 0);
    }
    __syncthreads();

#pragma unroll
    for (int ks = 0; ks < 2; ++ks) {
      bf16x8 a[4], b[4];
#pragma unroll
      for (int i = 0; i < 4; ++i) {
        int row = wm * 64 + i * 16 + lr;
        a[i] = *(const bf16x8*)&As[row * 64 + (((ks * 4 + lh) ^ swz) * 8)];
      }
#pragma unroll
      for (int j = 0; j < 4; ++j) {
        int row = wn * 64 + j * 16 + lr;
        b[j] = *(const bf16x8*)&Bs[row * 64 + (((ks * 4 + lh) ^ swz) * 8)];
      }
#pragma unroll
      for (int i = 0; i < 4; ++i)
#pragma unroll
        for (int j = 0; j < 4; ++j)
          acc[i][j] = __builtin_amdgcn_mfma_f32_16x16x32_bf16(a[i], b[j], acc[i][j], 0, 0, 0);
    }
  }

  float bv[4];
#pragma unroll
  for (int j = 0; j < 4; ++j)
    bv[j] = bias[n0 + wn * 64 + j * 16 + lr];
#pragma unroll
  for (int i = 0; i < 4; ++i)
#pragma unroll
    for (int j = 0; j < 4; ++j) {
      int n = n0 + wn * 64 + j * 16 + lr;
#pragma unroll
      for (int r = 0; r < 4; ++r) {
        int m = m0 + wm * 64 + i * 16 + lh * 4 + r;
        xp[(size_t)m * G3 + n] = (__hip_bfloat16)(acc[i][j][r] + bv[j]);
      }
    }
}

// ---------------------------------------------------------------------------
// Persistent GRU recurrence, v9: R7 protocol + 2 blocks/CU TLP overlap.
//   Grid 512: bt = idx&15 (16 batch rows, sync group of 32 blocks),
//             jt = idx>>4 (0..31, 16 j-cols each).
//   Co-resident blocks belong to different groups -> while one block's
//   leader polls, the sibling block's waves use the SIMDs.
//   Per wave: K-slice 128, 12 MFMA; W = 12 pinned frags (48 VGPR).
//   Protocol per step (R7-proven): batched coherent h loads; relaxed h
//   store; xp(t+1) prefetch BEFORE pre-flag barrier; leader flag store +
//   sleep-throttled poll of the 128-B group line; post barrier.
// ---------------------------------------------------------------------------
__global__ __launch_bounds__(256, 2) void gru_persist(
    __hip_bfloat16* __restrict__ hbA, __hip_bfloat16* __restrict__ hbB,
    float* __restrict__ h32,
    const __hip_bfloat16* __restrict__ xp,
    const __hip_bfloat16* __restrict__ WrT,
    const float* __restrict__ br,
    int* slots)                               // [16][32] ints (128 B / group)
{
  __shared__ float red[4][16][49];            // 12.5 KB

  const int tid = threadIdx.x;
  const int bt = blockIdx.x & 15;
  const int jt = blockIdx.x >> 4;             // 0..31
  const int wave = tid >> 6, l = tid & 63;
  const int lr = l & 15, lh = l >> 4;

  // ---- one-time: W fragments -> registers (12 x 16B per lane), pinned ----
  // gate f, col j = jt*16+lr, K-slice wave*128 + ks*32 + lh*8
  bf16x8 wfrag[4][3];
#pragma unroll
  for (int f = 0; f < 3; ++f) {
    int n = f * HID + jt * 16 + lr;
    const __hip_bfloat16* wp = &WrT[(size_t)n * HID + wave * 128 + lh * 8];
#pragma unroll
    for (int ks = 0; ks < 4; ++ks)
      wfrag[ks][f] = *(const bf16x8*)&wp[ks * 32];
  }
  asm volatile(""
      : "+v"(wfrag[0][0]), "+v"(wfrag[0][1]), "+v"(wfrag[0][2]),
        "+v"(wfrag[1][0]), "+v"(wfrag[1][1]), "+v"(wfrag[1][2]),
        "+v"(wfrag[2][0]), "+v"(wfrag[2][1]), "+v"(wfrag[2][2]),
        "+v"(wfrag[3][0]), "+v"(wfrag[3][1]), "+v"(wfrag[3][2]));

  // ---- per-thread epilogue ownership: row m, col c (1 output) ----
  const int m = tid >> 4, c = tid & 15;
  const int b = bt * 16 + m;
  const int jg = jt * 16 + c;
  const float brz = br[jg], brr = br[HID + jg], brh = br[2 * HID + jg];
  float hreg = 0.f;

  // preload xp for t=0
  float xz, xr, xh;
  {
    const __hip_bfloat16* xq = &xp[((size_t)b * SEQ + 0) * G3 + jg];
    xz = (float)xq[0];
    xr = (float)xq[HID];
    xh = (float)xq[2 * HID];
  }

  // per-lane h-fragment base (bytes): row bt*16+lr, K offset wave*128+lh*8
  const char* baseA = (const char*)hbA + ((size_t)(bt * 16 + lr) * HID + wave * 128 + lh * 8) * 2;
  const char* baseB = (const char*)hbB + ((size_t)(bt * 16 + lr) * HID + wave * 128 + lh * 8) * 2;

  for (int t = 0; t < SEQ; ++t) {
    const char* hp = (t & 1) ? baseB : baseA;
    __hip_bfloat16* nxt = (t & 1) ? hbA : hbB;

    // ---- h fragments: 4 batched coherent 16B loads, ONE waitcnt ----
    i32x4v r0, r1, r2, r3;
    asm volatile(
        "global_load_dwordx4 %0, %4, off sc0 sc1\n\t"
        "global_load_dwordx4 %1, %4, off offset:64 sc0 sc1\n\t"
        "global_load_dwordx4 %2, %4, off offset:128 sc0 sc1\n\t"
        "global_load_dwordx4 %3, %4, off offset:192 sc0 sc1\n\t"
        "s_waitcnt vmcnt(0)"
        : "=&v"(r0), "=&v"(r1), "=&v"(r2), "=&v"(r3)
        : "v"(hp)
        : "memory");
    union { i32x4v q; bf16x8 v; } u0, u1, u2, u3;
    u0.q = r0; u1.q = r1; u2.q = r2; u3.q = r3;
    bf16x8 afrag[4] = {u0.v, u1.v, u2.v, u3.v};

    // ---- MFMA: 12, pure register operands ----
    f32x4 acc[3] = {};
#pragma unroll
    for (int ks = 0; ks < 4; ++ks)
#pragma unroll
      for (int f = 0; f < 3; ++f)
        acc[f] = __builtin_amdgcn_mfma_f32_16x16x32_bf16(afrag[ks], wfrag[ks][f], acc[f], 0, 0, 0);

#pragma unroll
    for (int f = 0; f < 3; ++f)
#pragma unroll
      for (int i = 0; i < 4; ++i)
        red[wave][lh * 4 + i][f * 16 + lr] = acc[f][i];
    __syncthreads();

    // ---- epilogue: 1 output per thread, sum 4 wave partials ----
    {
      float rz = red[0][m][c]      + red[1][m][c]      + red[2][m][c]      + red[3][m][c];
      float rr = red[0][m][16 + c] + red[1][m][16 + c] + red[2][m][16 + c] + red[3][m][16 + c];
      float rh = red[0][m][32 + c] + red[1][m][32 + c] + red[2][m][32 + c] + red[3][m][32 + c];
      rz += brz; rr += brr; rh += brh;
      float z  = 1.f / (1.f + __expf(-(xz + rz)));
      float rg = 1.f / (1.f + __expf(-(xr + rr)));
      float hh = fmaxf(xh + rg * rh, 0.f);
      hreg = z * hreg + (1.f - z) * hh;

      if (t < SEQ - 1) {
        __hip_bfloat16 h0 = (__hip_bfloat16)hreg;
        __hip_atomic_store(
            (unsigned short*)&nxt[(size_t)b * HID + jg],
            *(unsigned short*)&h0,
            __ATOMIC_RELAXED, __HIP_MEMORY_SCOPE_AGENT);

        // xp(t+1) prefetch — R7 position: before the pre-flag barrier
        const __hip_bfloat16* xq = &xp[((size_t)b * SEQ + t + 1) * G3 + jg];
        xz = (float)xq[0];
        xr = (float)xq[HID];
        xh = (float)xq[2 * HID];
      }
    }

    // ---- group barrier: R7 protocol, 32-member flag line ----
    if (t < SEQ - 1) {
      __syncthreads();   // drains all waves' vmcnt -> h stores visible
      if (tid == 0) {
        __hip_atomic_store(&slots[bt * 32 + jt], t + 1,
                           __ATOMIC_RELAXED, __HIP_MEMORY_SCOPE_AGENT);
        const char* fl = (const char*)&slots[bt * 32];
        for (;;) {
          i32x4v p0, p1, p2, p3, p4, p5, p6, p7;
          asm volatile(
              "global_load_dwordx4 %0, %8, off sc0 sc1\n\t"
              "global_load_dwordx4 %1, %8, off offset:16 sc0 sc1\n\t"
              "global_load_dwordx4 %2, %8, off offset:32 sc0 sc1\n\t"
              "global_load_dwordx4 %3, %8, off offset:48 sc0 sc1\n\t"
              "global_load_dwordx4 %4, %8, off offset:64 sc0 sc1\n\t"
              "global_load_dwordx4 %5, %8, off offset:80 sc0 sc1\n\t"
              "global_load_dwordx4 %6, %8, off offset:96 sc0 sc1\n\t"
              "global_load_dwordx4 %7, %8, off offset:112 sc0 sc1\n\t"
              "s_waitcnt vmcnt(0)"
              : "=&v"(p0), "=&v"(p1), "=&v"(p2), "=&v"(p3),
                "=&v"(p4), "=&v"(p5), "=&v"(p6), "=&v"(p7)
              : "v"(fl)
              : "memory");
          int t1 = t + 1;
          int ok = (p0[0] >= t1) & (p0[1] >= t1) & (p0[2] >= t1) & (p0[3] >= t1) &
                   (p1[0] >= t1) & (p1[1] >= t1) & (p1[2] >= t1) & (p1[3] >= t1) &
                   (p2[0] >= t1) & (p2[1] >= t1) & (p2[2] >= t1) & (p2[3] >= t1) &
                   (p3[0] >= t1) & (p3[1] >= t1) & (p3[2] >= t1) & (p3[3] >= t1) &
                   (p4[0] >= t1) & (p4[1] >= t1) & (p4[2] >= t1) & (p4[3] >= t1) &
                   (p5[0] >= t1) & (p5[1] >= t1) & (p5[2] >= t1) & (p5[3] >= t1) &
                   (p6[0] >= t1) & (p6[1] >= t1) & (p6[2] >= t1) & (p6[3] >= t1) &
                   (p7[0] >= t1) & (p7[1] >= t1) & (p7[2] >= t1) & (p7[3] >= t1);
          if (ok) break;
          __builtin_amdgcn_s_sleep(1);
        }
      }
      __syncthreads();
    }
  }

  // final fp32 h
  h32[(size_t)b * HID + jg] = hreg;
}

// ---------------------------------------------------------------------------
// head: out[b] = h32[b][:] . Wd + bd
// ---------------------------------------------------------------------------
__global__ __launch_bounds__(64) void head_kernel(
    const float* __restrict__ h32, const float* __restrict__ Wd,
    const float* __restrict__ bd, float* __restrict__ out)
{
  int b = blockIdx.x, l = threadIdx.x;
  const float* hr = &h32[(size_t)b * HID];
  float s = 0.f;
#pragma unroll
  for (int i = 0; i < 8; ++i)
    s += hr[l + i * 64] * Wd[l + i * 64];
#pragma unroll
  for (int off = 32; off; off >>= 1) s += __shfl_down(s, off);
  if (l == 0) out[b] = s + bd[0];
}

// ---------------------------------------------------------------------------
extern "C" void kernel_launch(void* const* d_in, const int* in_sizes, int n_in,
                              void* d_out, int out_size, void* d_ws, size_t ws_size,
                              hipStream_t stream) {
  const float* x    = (const float*)d_in[0];
  const float* Wk   = (const float*)d_in[1];
  const float* Wr   = (const float*)d_in[2];
  const float* bias = (const float*)d_in[3];
  const float* Wd   = (const float*)d_in[4];
  const float* bd   = (const float*)d_in[5];
  float* out = (float*)d_out;

  char* ws = (char*)d_ws;
  size_t off = 0;
  __hip_bfloat16* xp  = (__hip_bfloat16*)(ws + off); off += (size_t)BATCH * SEQ * G3 * 2;
  __hip_bfloat16* xb  = (__hip_bfloat16*)(ws + off); off += (size_t)BATCH * SEQ * FEAT * 2;
  __hip_bfloat16* WkT = (__hip_bfloat16*)(ws + off); off += (size_t)G3 * FEAT * 2;
  __hip_bfloat16* WrT = (__hip_bfloat16*)(ws + off); off += (size_t)G3 * HID * 2;
  float*          h32 = (float*)(ws + off);          off += (size_t)BATCH * HID * 4;
  __hip_bfloat16* hb0 = (__hip_bfloat16*)(ws + off); off += (size_t)BATCH * HID * 2;
  __hip_bfloat16* hb1 = (__hip_bfloat16*)(ws + off); off += (size_t)BATCH * HID * 2;
  int*            slots = (int*)(ws + off);          off += 16 * 32 * sizeof(int);

  convert_bf16<<<(BATCH * SEQ * FEAT) / (256 * 8), 256, 0, stream>>>(x, xb, BATCH * SEQ * FEAT);
  transpose_convert<<<dim3(G3 / 32, FEAT / 32), 256, 0, stream>>>(Wk, WkT);
  transpose_convert<<<dim3(G3 / 32, HID  / 32), 256, 0, stream>>>(Wr, WrT);

  proj_mfma<<<dim3(G3 / 128, (BATCH * SEQ) / 128), 256, 0, stream>>>(xb, WkT, bias, xp);

  hipMemsetAsync(hb0, 0, (size_t)BATCH * HID * sizeof(__hip_bfloat16), stream);
  hipMemsetAsync(slots, 0, 16 * 32 * sizeof(int), stream);

  const float* br = bias + G3;
  {
    void* args[] = {(void*)&hb0, (void*)&hb1, (void*)&h32, (void*)&xp,
                    (void*)&WrT, (void*)&br, (void*)&slots};
    hipLaunchCooperativeKernel((void*)gru_persist, dim3(512), dim3(256),
                               args, 0, stream);
  }

  head_kernel<<<256, 64, 0, stream>>>(h32, Wd, bd, out);
}

// Round 14
// 457.727 us; speedup vs baseline: 1.6454x; 1.6454x over previous
//
#include <hip/hip_runtime.h>
#include <hip/hip_bf16.h>
#include <math.h>

constexpr int BATCH = 256;
constexpr int SEQ   = 128;
constexpr int FEAT  = 512;
constexpr int HID   = 512;
constexpr int G3    = 1536;

typedef __bf16 bf16x8 __attribute__((ext_vector_type(8)));
typedef float  f32x4  __attribute__((ext_vector_type(4)));
typedef int    i32x4v __attribute__((ext_vector_type(4)));

// ---------------------------------------------------------------------------
// fp32 -> bf16 convert (vectorized, 8/thread)
// ---------------------------------------------------------------------------
__global__ __launch_bounds__(256) void convert_bf16(
    const float* __restrict__ in, __hip_bfloat16* __restrict__ out, int n)
{
  int i = (blockIdx.x * 256 + threadIdx.x) * 8;
  if (i >= n) return;
  float4 v0 = *(const float4*)&in[i];
  float4 v1 = *(const float4*)&in[i + 4];
  __hip_bfloat16 o[8];
  o[0] = (__hip_bfloat16)v0.x; o[1] = (__hip_bfloat16)v0.y;
  o[2] = (__hip_bfloat16)v0.z; o[3] = (__hip_bfloat16)v0.w;
  o[4] = (__hip_bfloat16)v1.x; o[5] = (__hip_bfloat16)v1.y;
  o[6] = (__hip_bfloat16)v1.z; o[7] = (__hip_bfloat16)v1.w;
  *(int4*)&out[i] = *(int4*)o;
}

// ---------------------------------------------------------------------------
// transpose + convert both weights in one dispatch:
//   z=0: Wk [512][1536] f32 -> WkT [1536][512] bf16
//   z=1: Wr [512][1536] f32 -> WrT [1536][512] bf16
// ---------------------------------------------------------------------------
__global__ __launch_bounds__(256) void transpose_convert2(
    const float* __restrict__ inA, __hip_bfloat16* __restrict__ outA,
    const float* __restrict__ inB, __hip_bfloat16* __restrict__ outB)
{
  __shared__ float tile[32][33];
  const float* in = blockIdx.z ? inB : inA;
  __hip_bfloat16* outT = blockIdx.z ? outB : outA;
  const int c0 = blockIdx.x * 32;
  const int r0 = blockIdx.y * 32;
  const int tid = threadIdx.x;
  {
    int row = tid >> 3, c4 = tid & 7;
    float4 v = *(const float4*)&in[(size_t)(r0 + row) * G3 + c0 + c4 * 4];
    tile[row][c4 * 4 + 0] = v.x;
    tile[row][c4 * 4 + 1] = v.y;
    tile[row][c4 * 4 + 2] = v.z;
    tile[row][c4 * 4 + 3] = v.w;
  }
  __syncthreads();
  {
    int rowT = tid >> 3, c4 = tid & 7;
    __hip_bfloat16 o[4];
#pragma unroll
    for (int e = 0; e < 4; ++e)
      o[e] = (__hip_bfloat16)tile[c4 * 4 + e][rowT];
    *(int2*)&outT[(size_t)(c0 + rowT) * FEAT + r0 + c4 * 4] = *(int2*)o;
  }
}

// ---------------------------------------------------------------------------
// proj: 128x128 tile, BK=64, single-buffered global_load_lds staging with
// XOR source/read swizzle; __launch_bounds__(256,3) (R12-proven: 77 us).
// ---------------------------------------------------------------------------
__global__ __launch_bounds__(256, 3) void proj_mfma(
    const __hip_bfloat16* __restrict__ xb, const __hip_bfloat16* __restrict__ WkT,
    const float* __restrict__ bias, __hip_bfloat16* __restrict__ xp)
{
  __shared__ __align__(16) __hip_bfloat16 As[128 * 64];
  __shared__ __align__(16) __hip_bfloat16 Bs[128 * 64];

  const int tid = threadIdx.x;
  const int wave = tid >> 6, l = tid & 63;
  const int wm = wave >> 1, wn = wave & 1;
  const int m0 = blockIdx.y * 128;
  const int n0 = blockIdx.x * 128;
  const int lr = l & 15, lh = l >> 4;
  const int swz = lr & 7;

  const int srow = l >> 3;
  const int schk = l & 7;
  const int wrow = wave * 32;

  f32x4 acc[4][4] = {};

  for (int k0 = 0; k0 < FEAT; k0 += 64) {
    __syncthreads();
#pragma unroll
    for (int i = 0; i < 4; ++i) {
      int r = wrow + i * 8 + srow;
      const __hip_bfloat16* srcA = &xb[(size_t)(m0 + r) * FEAT + k0 + ((schk ^ srow) * 8)];
      __builtin_amdgcn_global_load_lds(
          (const __attribute__((address_space(1))) void*)srcA,
          (__attribute__((address_space(3))) void*)&As[(wrow + i * 8) * 64], 16, 0, 0);
    }
#pragma unroll
    for (int i = 0; i < 4; ++i) {
      int r = wrow + i * 8 + srow;
      const __hip_bfloat16* srcB = &WkT[(size_t)(n0 + r) * FEAT + k0 + ((schk ^ srow) * 8)];
      __builtin_amdgcn_global_load_lds(
          (const __attribute__((address_space(1))) void*)srcB,
          (__attribute__((address_space(3))) void*)&Bs[(wrow + i * 8) * 64], 16, 0, 0);
    }
    __syncthreads();

#pragma unroll
    for (int ks = 0; ks < 2; ++ks) {
      bf16x8 a[4], b[4];
#pragma unroll
      for (int i = 0; i < 4; ++i) {
        int row = wm * 64 + i * 16 + lr;
        a[i] = *(const bf16x8*)&As[row * 64 + (((ks * 4 + lh) ^ swz) * 8)];
      }
#pragma unroll
      for (int j = 0; j < 4; ++j) {
        int row = wn * 64 + j * 16 + lr;
        b[j] = *(const bf16x8*)&Bs[row * 64 + (((ks * 4 + lh) ^ swz) * 8)];
      }
#pragma unroll
      for (int i = 0; i < 4; ++i)
#pragma unroll
        for (int j = 0; j < 4; ++j)
          acc[i][j] = __builtin_amdgcn_mfma_f32_16x16x32_bf16(a[i], b[j], acc[i][j], 0, 0, 0);
    }
  }

  float bv[4];
#pragma unroll
  for (int j = 0; j < 4; ++j)
    bv[j] = bias[n0 + wn * 64 + j * 16 + lr];
#pragma unroll
  for (int i = 0; i < 4; ++i)
#pragma unroll
    for (int j = 0; j < 4; ++j) {
      int n = n0 + wn * 64 + j * 16 + lr;
#pragma unroll
      for (int r = 0; r < 4; ++r) {
        int m = m0 + wm * 64 + i * 16 + lh * 4 + r;
        xp[(size_t)m * G3 + n] = (__hip_bfloat16)(acc[i][j][r] + bv[j]);
      }
    }
}

// ---------------------------------------------------------------------------
// Persistent GRU recurrence — R7 VERBATIM (measured optimum: 338 us,
// 2.64 us/step across 7 protocol variants R8..R13).
//   - register-pinned W (24 frags/lane), batched coherent h loads (one
//     vmcnt), relaxed u32 h store, xp(t+1) prefetch before the pre-flag
//     barrier, leader-only flag store + sleep-throttled leader poll of the
//     64-B group flag line, post barrier.
// Grid 256: blockIdx.x = jt*16 + bt.
// ---------------------------------------------------------------------------
__global__ __launch_bounds__(256, 1) void gru_persist(
    __hip_bfloat16* __restrict__ hbA, __hip_bfloat16* __restrict__ hbB,
    float* __restrict__ h32,
    const __hip_bfloat16* __restrict__ xp,
    const __hip_bfloat16* __restrict__ WrT,
    const float* __restrict__ br,
    int* slots)                               // [16][16] ints
{
  __shared__ float red[2 * 16 * 100];

  const int tid = threadIdx.x;
  const int bt = blockIdx.x & 15;
  const int jt = blockIdx.x >> 4;
  const int wave = tid >> 6, l = tid & 63;
  const int kh = wave & 1, ch = wave >> 1;
  const int lr = l & 15, lh = l >> 4;

  // ---- one-time: W fragments -> registers (24 x 16B per lane), pinned ----
  bf16x8 wfrag[8][3];
#pragma unroll
  for (int f = 0; f < 3; ++f) {
    int r = ch * 48 + f * 16 + lr;
    int n = (r >> 5) * HID + jt * 32 + (r & 31);
    const __hip_bfloat16* wp = &WrT[(size_t)n * HID + kh * 256 + lh * 8];
#pragma unroll
    for (int ks = 0; ks < 8; ++ks)
      wfrag[ks][f] = *(const bf16x8*)&wp[ks * 32];
  }
  asm volatile(""
      : "+v"(wfrag[0][0]), "+v"(wfrag[0][1]), "+v"(wfrag[0][2]),
        "+v"(wfrag[1][0]), "+v"(wfrag[1][1]), "+v"(wfrag[1][2]),
        "+v"(wfrag[2][0]), "+v"(wfrag[2][1]), "+v"(wfrag[2][2]),
        "+v"(wfrag[3][0]), "+v"(wfrag[3][1]), "+v"(wfrag[3][2]),
        "+v"(wfrag[4][0]), "+v"(wfrag[4][1]), "+v"(wfrag[4][2]),
        "+v"(wfrag[5][0]), "+v"(wfrag[5][1]), "+v"(wfrag[5][2]),
        "+v"(wfrag[6][0]), "+v"(wfrag[6][1]), "+v"(wfrag[6][2]),
        "+v"(wfrag[7][0]), "+v"(wfrag[7][1]), "+v"(wfrag[7][2]));

  // ---- per-thread epilogue ownership ----
  const int m = tid >> 4, q4 = tid & 15;
  const int b = bt * 16 + m;
  const int jl0 = q4 * 2;
  const int jg0 = jt * 32 + jl0;
  float brz[2], brr[2], brh[2], hreg[2];
#pragma unroll
  for (int p = 0; p < 2; ++p) {
    brz[p] = br[jg0 + p];
    brr[p] = br[HID + jg0 + p];
    brh[p] = br[2 * HID + jg0 + p];
    hreg[p] = 0.f;
  }

  float xzv[2], xrv[2], xhv[2];
  {
    const __hip_bfloat16* xb_ = &xp[((size_t)b * SEQ + 0) * G3 + jg0];
    unsigned int uz = *(const unsigned int*)&xb_[0];
    unsigned int ur = *(const unsigned int*)&xb_[HID];
    unsigned int uh = *(const unsigned int*)&xb_[2 * HID];
    xzv[0] = (float)((__hip_bfloat16*)&uz)[0]; xzv[1] = (float)((__hip_bfloat16*)&uz)[1];
    xrv[0] = (float)((__hip_bfloat16*)&ur)[0]; xrv[1] = (float)((__hip_bfloat16*)&ur)[1];
    xhv[0] = (float)((__hip_bfloat16*)&uh)[0]; xhv[1] = (float)((__hip_bfloat16*)&uh)[1];
  }

  // per-lane h-fragment base (bytes): row (bt*16+lr), K-offset kh*256+lh*8 bf16
  const char* baseA = (const char*)hbA + ((size_t)(bt * 16 + lr) * HID + kh * 256 + lh * 8) * 2;
  const char* baseB = (const char*)hbB + ((size_t)(bt * 16 + lr) * HID + kh * 256 + lh * 8) * 2;

  for (int t = 0; t < SEQ; ++t) {
    const char* hp = (t & 1) ? baseB : baseA;
    __hip_bfloat16* nxt = (t & 1) ? hbA : hbB;

    // ---- h fragments: 8 batched coherent 16B loads, ONE waitcnt ----
    i32x4v r0, r1, r2, r3, r4, r5, r6, r7;
    asm volatile(
        "global_load_dwordx4 %0, %8, off sc0 sc1\n\t"
        "global_load_dwordx4 %1, %8, off offset:64 sc0 sc1\n\t"
        "global_load_dwordx4 %2, %8, off offset:128 sc0 sc1\n\t"
        "global_load_dwordx4 %3, %8, off offset:192 sc0 sc1\n\t"
        "global_load_dwordx4 %4, %8, off offset:256 sc0 sc1\n\t"
        "global_load_dwordx4 %5, %8, off offset:320 sc0 sc1\n\t"
        "global_load_dwordx4 %6, %8, off offset:384 sc0 sc1\n\t"
        "global_load_dwordx4 %7, %8, off offset:448 sc0 sc1\n\t"
        "s_waitcnt vmcnt(0)"
        : "=&v"(r0), "=&v"(r1), "=&v"(r2), "=&v"(r3),
          "=&v"(r4), "=&v"(r5), "=&v"(r6), "=&v"(r7)
        : "v"(hp)
        : "memory");
    union { i32x4v q; bf16x8 v; } u0, u1, u2, u3, u4, u5, u6, u7;
    u0.q = r0; u1.q = r1; u2.q = r2; u3.q = r3;
    u4.q = r4; u5.q = r5; u6.q = r6; u7.q = r7;
    bf16x8 afrag[8] = {u0.v, u1.v, u2.v, u3.v, u4.v, u5.v, u6.v, u7.v};

    // ---- MFMA: pure register operands ----
    f32x4 acc[3] = {};
#pragma unroll
    for (int ks = 0; ks < 8; ++ks)
#pragma unroll
      for (int f = 0; f < 3; ++f)
        acc[f] = __builtin_amdgcn_mfma_f32_16x16x32_bf16(afrag[ks], wfrag[ks][f], acc[f], 0, 0, 0);

#pragma unroll
    for (int f = 0; f < 3; ++f)
#pragma unroll
      for (int i = 0; i < 4; ++i)
        red[kh * 1600 + (lh * 4 + i) * 100 + ch * 48 + f * 16 + lr] = acc[f][i];
    __syncthreads();

    // ---- epilogue ----
    {
      float hn[2];
#pragma unroll
      for (int p = 0; p < 2; ++p) {
        int jl = jl0 + p;
        float rz = red[m * 100 + jl]      + red[1600 + m * 100 + jl];
        float rr = red[m * 100 + 32 + jl] + red[1600 + m * 100 + 32 + jl];
        float rh = red[m * 100 + 64 + jl] + red[1600 + m * 100 + 64 + jl];
        rz += brz[p]; rr += brr[p]; rh += brh[p];
        float z  = 1.f / (1.f + __expf(-(xzv[p] + rz)));
        float rg = 1.f / (1.f + __expf(-(xrv[p] + rr)));
        float hh = fmaxf(xhv[p] + rg * rh, 0.f);
        hn[p] = z * hreg[p] + (1.f - z) * hh;
        hreg[p] = hn[p];
      }
      if (t < SEQ - 1) {
        __hip_bfloat16 h0 = (__hip_bfloat16)hn[0], h1 = (__hip_bfloat16)hn[1];
        unsigned int pk = (unsigned int)*(unsigned short*)&h0 |
                          ((unsigned int)*(unsigned short*)&h1 << 16);
        __hip_atomic_store(
            (unsigned int*)&nxt[(size_t)b * HID + jg0], pk,
            __ATOMIC_RELAXED, __HIP_MEMORY_SCOPE_AGENT);

        // xp(t+1) prefetch — R7 position (before the pre-flag barrier)
        const __hip_bfloat16* xb_ = &xp[((size_t)b * SEQ + t + 1) * G3 + jg0];
        unsigned int uz = *(const unsigned int*)&xb_[0];
        unsigned int ur = *(const unsigned int*)&xb_[HID];
        unsigned int uh = *(const unsigned int*)&xb_[2 * HID];
        xzv[0] = (float)((__hip_bfloat16*)&uz)[0]; xzv[1] = (float)((__hip_bfloat16*)&uz)[1];
        xrv[0] = (float)((__hip_bfloat16*)&ur)[0]; xrv[1] = (float)((__hip_bfloat16*)&ur)[1];
        xhv[0] = (float)((__hip_bfloat16*)&uh)[0]; xhv[1] = (float)((__hip_bfloat16*)&uh)[1];
      }
    }

    // ---- group barrier: single-writer flags, leader batched poll ----
    if (t < SEQ - 1) {
      __syncthreads();   // drains all waves' vmcnt -> h stores visible
      if (tid == 0) {
        __hip_atomic_store(&slots[bt * 16 + jt], t + 1,
                           __ATOMIC_RELAXED, __HIP_MEMORY_SCOPE_AGENT);
        const char* fl = (const char*)&slots[bt * 16];
        for (;;) {
          i32x4v p0, p1, p2, p3;
          asm volatile(
              "global_load_dwordx4 %0, %4, off sc0 sc1\n\t"
              "global_load_dwordx4 %1, %4, off offset:16 sc0 sc1\n\t"
              "global_load_dwordx4 %2, %4, off offset:32 sc0 sc1\n\t"
              "global_load_dwordx4 %3, %4, off offset:48 sc0 sc1\n\t"
              "s_waitcnt vmcnt(0)"
              : "=&v"(p0), "=&v"(p1), "=&v"(p2), "=&v"(p3)
              : "v"(fl)
              : "memory");
          int t1 = t + 1;
          int ok = (p0[0] >= t1) & (p0[1] >= t1) & (p0[2] >= t1) & (p0[3] >= t1) &
                   (p1[0] >= t1) & (p1[1] >= t1) & (p1[2] >= t1) & (p1[3] >= t1) &
                   (p2[0] >= t1) & (p2[1] >= t1) & (p2[2] >= t1) & (p2[3] >= t1) &
                   (p3[0] >= t1) & (p3[1] >= t1) & (p3[2] >= t1) & (p3[3] >= t1);
          if (ok) break;
          __builtin_amdgcn_s_sleep(1);
        }
      }
      __syncthreads();
    }
  }

  // final fp32 h
#pragma unroll
  for (int p = 0; p < 2; ++p)
    h32[(size_t)b * HID + jg0 + p] = hreg[p];
}

// ---------------------------------------------------------------------------
// head: out[b] = h32[b][:] . Wd + bd
// ---------------------------------------------------------------------------
__global__ __launch_bounds__(64) void head_kernel(
    const float* __restrict__ h32, const float* __restrict__ Wd,
    const float* __restrict__ bd, float* __restrict__ out)
{
  int b = blockIdx.x, l = threadIdx.x;
  const float* hr = &h32[(size_t)b * HID];
  float s = 0.f;
#pragma unroll
  for (int i = 0; i < 8; ++i)
    s += hr[l + i * 64] * Wd[l + i * 64];
#pragma unroll
  for (int off = 32; off; off >>= 1) s += __shfl_down(s, off);
  if (l == 0) out[b] = s + bd[0];
}

// ---------------------------------------------------------------------------
extern "C" void kernel_launch(void* const* d_in, const int* in_sizes, int n_in,
                              void* d_out, int out_size, void* d_ws, size_t ws_size,
                              hipStream_t stream) {
  const float* x    = (const float*)d_in[0];
  const float* Wk   = (const float*)d_in[1];
  const float* Wr   = (const float*)d_in[2];
  const float* bias = (const float*)d_in[3];
  const float* Wd   = (const float*)d_in[4];
  const float* bd   = (const float*)d_in[5];
  float* out = (float*)d_out;

  char* ws = (char*)d_ws;
  size_t off = 0;
  __hip_bfloat16* xp  = (__hip_bfloat16*)(ws + off); off += (size_t)BATCH * SEQ * G3 * 2;
  __hip_bfloat16* xb  = (__hip_bfloat16*)(ws + off); off += (size_t)BATCH * SEQ * FEAT * 2;
  __hip_bfloat16* WkT = (__hip_bfloat16*)(ws + off); off += (size_t)G3 * FEAT * 2;
  __hip_bfloat16* WrT = (__hip_bfloat16*)(ws + off); off += (size_t)G3 * HID * 2;
  float*          h32 = (float*)(ws + off);          off += (size_t)BATCH * HID * 4;
  __hip_bfloat16* hb0 = (__hip_bfloat16*)(ws + off); off += (size_t)BATCH * HID * 2;
  __hip_bfloat16* hb1 = (__hip_bfloat16*)(ws + off); off += (size_t)BATCH * HID * 2;
  int*            slots = (int*)(ws + off);          off += 16 * 16 * sizeof(int);

  convert_bf16<<<(BATCH * SEQ * FEAT) / (256 * 8), 256, 0, stream>>>(x, xb, BATCH * SEQ * FEAT);
  transpose_convert2<<<dim3(G3 / 32, FEAT / 32, 2), 256, 0, stream>>>(Wk, WkT, Wr, WrT);

  proj_mfma<<<dim3(G3 / 128, (BATCH * SEQ) / 128), 256, 0, stream>>>(xb, WkT, bias, xp);

  hipMemsetAsync(hb0, 0, (size_t)BATCH * HID * sizeof(__hip_bfloat16), stream);
  hipMemsetAsync(slots, 0, 16 * 16 * sizeof(int), stream);

  const float* br = bias + G3;
  {
    void* args[] = {(void*)&hb0, (void*)&hb1, (void*)&h32, (void*)&xp,
                    (void*)&WrT, (void*)&br, (void*)&slots};
    hipLaunchCooperativeKernel((void*)gru_persist, dim3(256), dim3(256),
                               args, 0, stream);
  }

  head_kernel<<<256, 64, 0, stream>>>(h32, Wd, bd, out);
}

// Round 16
// 453.628 us; speedup vs baseline: 1.6603x; 1.0090x over previous
//
#include <hip/hip_runtime.h>
#include <hip/hip_bf16.h>
#include <math.h>

constexpr int BATCH = 256;
constexpr int SEQ   = 128;
constexpr int FEAT  = 512;
constexpr int HID   = 512;
constexpr int G3    = 1536;

typedef __bf16 bf16x8 __attribute__((ext_vector_type(8)));
typedef float  f32x4  __attribute__((ext_vector_type(4)));
typedef int    i32x4v __attribute__((ext_vector_type(4)));

// ---------------------------------------------------------------------------
// fp32 -> bf16 convert (vectorized, 8/thread)
// ---------------------------------------------------------------------------
__global__ __launch_bounds__(256) void convert_bf16(
    const float* __restrict__ in, __hip_bfloat16* __restrict__ out, int n)
{
  int i = (blockIdx.x * 256 + threadIdx.x) * 8;
  if (i >= n) return;
  float4 v0 = *(const float4*)&in[i];
  float4 v1 = *(const float4*)&in[i + 4];
  __hip_bfloat16 o[8];
  o[0] = (__hip_bfloat16)v0.x; o[1] = (__hip_bfloat16)v0.y;
  o[2] = (__hip_bfloat16)v0.z; o[3] = (__hip_bfloat16)v0.w;
  o[4] = (__hip_bfloat16)v1.x; o[5] = (__hip_bfloat16)v1.y;
  o[6] = (__hip_bfloat16)v1.z; o[7] = (__hip_bfloat16)v1.w;
  *(int4*)&out[i] = *(int4*)o;
}

// ---------------------------------------------------------------------------
// transpose + convert both weights in one dispatch:
//   z=0: Wk [512][1536] f32 -> WkT [1536][512] bf16
//   z=1: Wr [512][1536] f32 -> WrT [1536][512] bf16
// ---------------------------------------------------------------------------
__global__ __launch_bounds__(256) void transpose_convert2(
    const float* __restrict__ inA, __hip_bfloat16* __restrict__ outA,
    const float* __restrict__ inB, __hip_bfloat16* __restrict__ outB)
{
  __shared__ float tile[32][33];
  const float* in = blockIdx.z ? inB : inA;
  __hip_bfloat16* outT = blockIdx.z ? outB : outA;
  const int c0 = blockIdx.x * 32;
  const int r0 = blockIdx.y * 32;
  const int tid = threadIdx.x;
  {
    int row = tid >> 3, c4 = tid & 7;
    float4 v = *(const float4*)&in[(size_t)(r0 + row) * G3 + c0 + c4 * 4];
    tile[row][c4 * 4 + 0] = v.x;
    tile[row][c4 * 4 + 1] = v.y;
    tile[row][c4 * 4 + 2] = v.z;
    tile[row][c4 * 4 + 3] = v.w;
  }
  __syncthreads();
  {
    int rowT = tid >> 3, c4 = tid & 7;
    __hip_bfloat16 o[4];
#pragma unroll
    for (int e = 0; e < 4; ++e)
      o[e] = (__hip_bfloat16)tile[c4 * 4 + e][rowT];
    *(int2*)&outT[(size_t)(c0 + rowT) * FEAT + r0 + c4 * 4] = *(int2*)o;
  }
}

// ---------------------------------------------------------------------------
// proj: 128x128 tile, BK=64, single-buffered global_load_lds staging with
// XOR source/read swizzle; __launch_bounds__(256,3) (R12-proven: 77 us).
// ---------------------------------------------------------------------------
__global__ __launch_bounds__(256, 3) void proj_mfma(
    const __hip_bfloat16* __restrict__ xb, const __hip_bfloat16* __restrict__ WkT,
    const float* __restrict__ bias, __hip_bfloat16* __restrict__ xp)
{
  __shared__ __align__(16) __hip_bfloat16 As[128 * 64];
  __shared__ __align__(16) __hip_bfloat16 Bs[128 * 64];

  const int tid = threadIdx.x;
  const int wave = tid >> 6, l = tid & 63;
  const int wm = wave >> 1, wn = wave & 1;
  const int m0 = blockIdx.y * 128;
  const int n0 = blockIdx.x * 128;
  const int lr = l & 15, lh = l >> 4;
  const int swz = lr & 7;

  const int srow = l >> 3;
  const int schk = l & 7;
  const int wrow = wave * 32;

  f32x4 acc[4][4] = {};

  for (int k0 = 0; k0 < FEAT; k0 += 64) {
    __syncthreads();
#pragma unroll
    for (int i = 0; i < 4; ++i) {
      int r = wrow + i * 8 + srow;
      const __hip_bfloat16* srcA = &xb[(size_t)(m0 + r) * FEAT + k0 + ((schk ^ srow) * 8)];
      __builtin_amdgcn_global_load_lds(
          (const __attribute__((address_space(1))) void*)srcA,
          (__attribute__((address_space(3))) void*)&As[(wrow + i * 8) * 64], 16, 0, 0);
    }
#pragma unroll
    for (int i = 0; i < 4; ++i) {
      int r = wrow + i * 8 + srow;
      const __hip_bfloat16* srcB = &WkT[(size_t)(n0 + r) * FEAT + k0 + ((schk ^ srow) * 8)];
      __builtin_amdgcn_global_load_lds(
          (const __attribute__((address_space(1))) void*)srcB,
          (__attribute__((address_space(3))) void*)&Bs[(wrow + i * 8) * 64], 16, 0, 0);
    }
    __syncthreads();

#pragma unroll
    for (int ks = 0; ks < 2; ++ks) {
      bf16x8 a[4], b[4];
#pragma unroll
      for (int i = 0; i < 4; ++i) {
        int row = wm * 64 + i * 16 + lr;
        a[i] = *(const bf16x8*)&As[row * 64 + (((ks * 4 + lh) ^ swz) * 8)];
      }
#pragma unroll
      for (int j = 0; j < 4; ++j) {
        int row = wn * 64 + j * 16 + lr;
        b[j] = *(const bf16x8*)&Bs[row * 64 + (((ks * 4 + lh) ^ swz) * 8)];
      }
#pragma unroll
      for (int i = 0; i < 4; ++i)
#pragma unroll
        for (int j = 0; j < 4; ++j)
          acc[i][j] = __builtin_amdgcn_mfma_f32_16x16x32_bf16(a[i], b[j], acc[i][j], 0, 0, 0);
    }
  }

  float bv[4];
#pragma unroll
  for (int j = 0; j < 4; ++j)
    bv[j] = bias[n0 + wn * 64 + j * 16 + lr];
#pragma unroll
  for (int i = 0; i < 4; ++i)
#pragma unroll
    for (int j = 0; j < 4; ++j) {
      int n = n0 + wn * 64 + j * 16 + lr;
#pragma unroll
      for (int r = 0; r < 4; ++r) {
        int m = m0 + wm * 64 + i * 16 + lh * 4 + r;
        xp[(size_t)m * G3 + n] = (__hip_bfloat16)(acc[i][j][r] + bv[j]);
      }
    }
}

// ---------------------------------------------------------------------------
// Persistent GRU recurrence — R7/R14 VERBATIM (measured optimum across 9
// protocol/structure variants; 2.7 us/step structural coherence floor).
//   - register-pinned W (24 frags/lane), batched coherent h loads (one
//     vmcnt), relaxed u32 h store, xp(t+1) prefetch before the pre-flag
//     barrier, leader-only flag store + sleep-throttled leader poll of the
//     64-B group flag line, post barrier.
// Grid 256: blockIdx.x = jt*16 + bt.
// ---------------------------------------------------------------------------
__global__ __launch_bounds__(256, 1) void gru_persist(
    __hip_bfloat16* __restrict__ hbA, __hip_bfloat16* __restrict__ hbB,
    float* __restrict__ h32,
    const __hip_bfloat16* __restrict__ xp,
    const __hip_bfloat16* __restrict__ WrT,
    const float* __restrict__ br,
    int* slots)                               // [16][16] ints
{
  __shared__ float red[2 * 16 * 100];

  const int tid = threadIdx.x;
  const int bt = blockIdx.x & 15;
  const int jt = blockIdx.x >> 4;
  const int wave = tid >> 6, l = tid & 63;
  const int kh = wave & 1, ch = wave >> 1;
  const int lr = l & 15, lh = l >> 4;

  // ---- one-time: W fragments -> registers (24 x 16B per lane), pinned ----
  bf16x8 wfrag[8][3];
#pragma unroll
  for (int f = 0; f < 3; ++f) {
    int r = ch * 48 + f * 16 + lr;
    int n = (r >> 5) * HID + jt * 32 + (r & 31);
    const __hip_bfloat16* wp = &WrT[(size_t)n * HID + kh * 256 + lh * 8];
#pragma unroll
    for (int ks = 0; ks < 8; ++ks)
      wfrag[ks][f] = *(const bf16x8*)&wp[ks * 32];
  }
  asm volatile(""
      : "+v"(wfrag[0][0]), "+v"(wfrag[0][1]), "+v"(wfrag[0][2]),
        "+v"(wfrag[1][0]), "+v"(wfrag[1][1]), "+v"(wfrag[1][2]),
        "+v"(wfrag[2][0]), "+v"(wfrag[2][1]), "+v"(wfrag[2][2]),
        "+v"(wfrag[3][0]), "+v"(wfrag[3][1]), "+v"(wfrag[3][2]),
        "+v"(wfrag[4][0]), "+v"(wfrag[4][1]), "+v"(wfrag[4][2]),
        "+v"(wfrag[5][0]), "+v"(wfrag[5][1]), "+v"(wfrag[5][2]),
        "+v"(wfrag[6][0]), "+v"(wfrag[6][1]), "+v"(wfrag[6][2]),
        "+v"(wfrag[7][0]), "+v"(wfrag[7][1]), "+v"(wfrag[7][2]));

  // ---- per-thread epilogue ownership ----
  const int m = tid >> 4, q4 = tid & 15;
  const int b = bt * 16 + m;
  const int jl0 = q4 * 2;
  const int jg0 = jt * 32 + jl0;
  float brz[2], brr[2], brh[2], hreg[2];
#pragma unroll
  for (int p = 0; p < 2; ++p) {
    brz[p] = br[jg0 + p];
    brr[p] = br[HID + jg0 + p];
    brh[p] = br[2 * HID + jg0 + p];
    hreg[p] = 0.f;
  }

  float xzv[2], xrv[2], xhv[2];
  {
    const __hip_bfloat16* xb_ = &xp[((size_t)b * SEQ + 0) * G3 + jg0];
    unsigned int uz = *(const unsigned int*)&xb_[0];
    unsigned int ur = *(const unsigned int*)&xb_[HID];
    unsigned int uh = *(const unsigned int*)&xb_[2 * HID];
    xzv[0] = (float)((__hip_bfloat16*)&uz)[0]; xzv[1] = (float)((__hip_bfloat16*)&uz)[1];
    xrv[0] = (float)((__hip_bfloat16*)&ur)[0]; xrv[1] = (float)((__hip_bfloat16*)&ur)[1];
    xhv[0] = (float)((__hip_bfloat16*)&uh)[0]; xhv[1] = (float)((__hip_bfloat16*)&uh)[1];
  }

  // per-lane h-fragment base (bytes): row (bt*16+lr), K-offset kh*256+lh*8 bf16
  const char* baseA = (const char*)hbA + ((size_t)(bt * 16 + lr) * HID + kh * 256 + lh * 8) * 2;
  const char* baseB = (const char*)hbB + ((size_t)(bt * 16 + lr) * HID + kh * 256 + lh * 8) * 2;

  for (int t = 0; t < SEQ; ++t) {
    const char* hp = (t & 1) ? baseB : baseA;
    __hip_bfloat16* nxt = (t & 1) ? hbA : hbB;

    // ---- h fragments: 8 batched coherent 16B loads, ONE waitcnt ----
    i32x4v r0, r1, r2, r3, r4, r5, r6, r7;
    asm volatile(
        "global_load_dwordx4 %0, %8, off sc0 sc1\n\t"
        "global_load_dwordx4 %1, %8, off offset:64 sc0 sc1\n\t"
        "global_load_dwordx4 %2, %8, off offset:128 sc0 sc1\n\t"
        "global_load_dwordx4 %3, %8, off offset:192 sc0 sc1\n\t"
        "global_load_dwordx4 %4, %8, off offset:256 sc0 sc1\n\t"
        "global_load_dwordx4 %5, %8, off offset:320 sc0 sc1\n\t"
        "global_load_dwordx4 %6, %8, off offset:384 sc0 sc1\n\t"
        "global_load_dwordx4 %7, %8, off offset:448 sc0 sc1\n\t"
        "s_waitcnt vmcnt(0)"
        : "=&v"(r0), "=&v"(r1), "=&v"(r2), "=&v"(r3),
          "=&v"(r4), "=&v"(r5), "=&v"(r6), "=&v"(r7)
        : "v"(hp)
        : "memory");
    union { i32x4v q; bf16x8 v; } u0, u1, u2, u3, u4, u5, u6, u7;
    u0.q = r0; u1.q = r1; u2.q = r2; u3.q = r3;
    u4.q = r4; u5.q = r5; u6.q = r6; u7.q = r7;
    bf16x8 afrag[8] = {u0.v, u1.v, u2.v, u3.v, u4.v, u5.v, u6.v, u7.v};

    // ---- MFMA: pure register operands ----
    f32x4 acc[3] = {};
#pragma unroll
    for (int ks = 0; ks < 8; ++ks)
#pragma unroll
      for (int f = 0; f < 3; ++f)
        acc[f] = __builtin_amdgcn_mfma_f32_16x16x32_bf16(afrag[ks], wfrag[ks][f], acc[f], 0, 0, 0);

#pragma unroll
    for (int f = 0; f < 3; ++f)
#pragma unroll
      for (int i = 0; i < 4; ++i)
        red[kh * 1600 + (lh * 4 + i) * 100 + ch * 48 + f * 16 + lr] = acc[f][i];
    __syncthreads();

    // ---- epilogue ----
    {
      float hn[2];
#pragma unroll
      for (int p = 0; p < 2; ++p) {
        int jl = jl0 + p;
        float rz = red[m * 100 + jl]      + red[1600 + m * 100 + jl];
        float rr = red[m * 100 + 32 + jl] + red[1600 + m * 100 + 32 + jl];
        float rh = red[m * 100 + 64 + jl] + red[1600 + m * 100 + 64 + jl];
        rz += brz[p]; rr += brr[p]; rh += brh[p];
        float z  = 1.f / (1.f + __expf(-(xzv[p] + rz)));
        float rg = 1.f / (1.f + __expf(-(xrv[p] + rr)));
        float hh = fmaxf(xhv[p] + rg * rh, 0.f);
        hn[p] = z * hreg[p] + (1.f - z) * hh;
        hreg[p] = hn[p];
      }
      if (t < SEQ - 1) {
        __hip_bfloat16 h0 = (__hip_bfloat16)hn[0], h1 = (__hip_bfloat16)hn[1];
        unsigned int pk = (unsigned int)*(unsigned short*)&h0 |
                          ((unsigned int)*(unsigned short*)&h1 << 16);
        __hip_atomic_store(
            (unsigned int*)&nxt[(size_t)b * HID + jg0], pk,
            __ATOMIC_RELAXED, __HIP_MEMORY_SCOPE_AGENT);

        // xp(t+1) prefetch — R7 position (before the pre-flag barrier)
        const __hip_bfloat16* xb_ = &xp[((size_t)b * SEQ + t + 1) * G3 + jg0];
        unsigned int uz = *(const unsigned int*)&xb_[0];
        unsigned int ur = *(const unsigned int*)&xb_[HID];
        unsigned int uh = *(const unsigned int*)&xb_[2 * HID];
        xzv[0] = (float)((__hip_bfloat16*)&uz)[0]; xzv[1] = (float)((__hip_bfloat16*)&uz)[1];
        xrv[0] = (float)((__hip_bfloat16*)&ur)[0]; xrv[1] = (float)((__hip_bfloat16*)&ur)[1];
        xhv[0] = (float)((__hip_bfloat16*)&uh)[0]; xhv[1] = (float)((__hip_bfloat16*)&uh)[1];
      }
    }

    // ---- group barrier: single-writer flags, leader batched poll ----
    if (t < SEQ - 1) {
      __syncthreads();   // drains all waves' vmcnt -> h stores visible
      if (tid == 0) {
        __hip_atomic_store(&slots[bt * 16 + jt], t + 1,
                           __ATOMIC_RELAXED, __HIP_MEMORY_SCOPE_AGENT);
        const char* fl = (const char*)&slots[bt * 16];
        for (;;) {
          i32x4v p0, p1, p2, p3;
          asm volatile(
              "global_load_dwordx4 %0, %4, off sc0 sc1\n\t"
              "global_load_dwordx4 %1, %4, off offset:16 sc0 sc1\n\t"
              "global_load_dwordx4 %2, %4, off offset:32 sc0 sc1\n\t"
              "global_load_dwordx4 %3, %4, off offset:48 sc0 sc1\n\t"
              "s_waitcnt vmcnt(0)"
              : "=&v"(p0), "=&v"(p1), "=&v"(p2), "=&v"(p3)
              : "v"(fl)
              : "memory");
          int t1 = t + 1;
          int ok = (p0[0] >= t1) & (p0[1] >= t1) & (p0[2] >= t1) & (p0[3] >= t1) &
                   (p1[0] >= t1) & (p1[1] >= t1) & (p1[2] >= t1) & (p1[3] >= t1) &
                   (p2[0] >= t1) & (p2[1] >= t1) & (p2[2] >= t1) & (p2[3] >= t1) &
                   (p3[0] >= t1) & (p3[1] >= t1) & (p3[2] >= t1) & (p3[3] >= t1);
          if (ok) break;
          __builtin_amdgcn_s_sleep(1);
        }
      }
      __syncthreads();
    }
  }

  // final fp32 h
#pragma unroll
  for (int p = 0; p < 2; ++p)
    h32[(size_t)b * HID + jg0 + p] = hreg[p];
}

// ---------------------------------------------------------------------------
// head: out[b] = h32[b][:] . Wd + bd
// ---------------------------------------------------------------------------
__global__ __launch_bounds__(64) void head_kernel(
    const float* __restrict__ h32, const float* __restrict__ Wd,
    const float* __restrict__ bd, float* __restrict__ out)
{
  int b = blockIdx.x, l = threadIdx.x;
  const float* hr = &h32[(size_t)b * HID];
  float s = 0.f;
#pragma unroll
  for (int i = 0; i < 8; ++i)
    s += hr[l + i * 64] * Wd[l + i * 64];
#pragma unroll
  for (int off = 32; off; off >>= 1) s += __shfl_down(s, off);
  if (l == 0) out[b] = s + bd[0];
}

// ---------------------------------------------------------------------------
extern "C" void kernel_launch(void* const* d_in, const int* in_sizes, int n_in,
                              void* d_out, int out_size, void* d_ws, size_t ws_size,
                              hipStream_t stream) {
  const float* x    = (const float*)d_in[0];
  const float* Wk   = (const float*)d_in[1];
  const float* Wr   = (const float*)d_in[2];
  const float* bias = (const float*)d_in[3];
  const float* Wd   = (const float*)d_in[4];
  const float* bd   = (const float*)d_in[5];
  float* out = (float*)d_out;

  char* ws = (char*)d_ws;
  size_t off = 0;
  __hip_bfloat16* xp  = (__hip_bfloat16*)(ws + off); off += (size_t)BATCH * SEQ * G3 * 2;
  __hip_bfloat16* xb  = (__hip_bfloat16*)(ws + off); off += (size_t)BATCH * SEQ * FEAT * 2;
  __hip_bfloat16* WkT = (__hip_bfloat16*)(ws + off); off += (size_t)G3 * FEAT * 2;
  __hip_bfloat16* WrT = (__hip_bfloat16*)(ws + off); off += (size_t)G3 * HID * 2;
  float*          h32 = (float*)(ws + off);          off += (size_t)BATCH * HID * 4;
  __hip_bfloat16* hb0 = (__hip_bfloat16*)(ws + off); off += (size_t)BATCH * HID * 2;
  __hip_bfloat16* hb1 = (__hip_bfloat16*)(ws + off); off += (size_t)BATCH * HID * 2;
  int*            slots = (int*)(ws + off);          off += 16 * 16 * sizeof(int);

  convert_bf16<<<(BATCH * SEQ * FEAT) / (256 * 8), 256, 0, stream>>>(x, xb, BATCH * SEQ * FEAT);
  transpose_convert2<<<dim3(G3 / 32, FEAT / 32, 2), 256, 0, stream>>>(Wk, WkT, Wr, WrT);

  proj_mfma<<<dim3(G3 / 128, (BATCH * SEQ) / 128), 256, 0, stream>>>(xb, WkT, bias, xp);

  hipMemsetAsync(hb0, 0, (size_t)BATCH * HID * sizeof(__hip_bfloat16), stream);
  hipMemsetAsync(slots, 0, 16 * 16 * sizeof(int), stream);

  const float* br = bias + G3;
  {
    void* args[] = {(void*)&hb0, (void*)&hb1, (void*)&h32, (void*)&xp,
                    (void*)&WrT, (void*)&br, (void*)&slots};
    hipLaunchCooperativeKernel((void*)gru_persist, dim3(256), dim3(256),
                               args, 0, stream);
  }

  head_kernel<<<256, 64, 0, stream>>>(h32, Wd, bd, out);
}